// Round 1
// baseline (624.174 us; speedup 1.0000x reference)
//
#include <hip/hip_runtime.h>

#define DEV static __device__ __forceinline__

typedef __attribute__((ext_vector_type(8))) short short8;
typedef __attribute__((ext_vector_type(4))) float f32x4;
typedef __attribute__((ext_vector_type(4))) unsigned short ushort4v;
typedef __attribute__((ext_vector_type(4))) float float4v;

#define DM 1024
#define NH 16
#define HD 64
#define NB 4
#define SS 2048
#define TOK 8192

DEV unsigned short f2bf(float f) {
  union { float f; unsigned u; } v; v.f = f;
  unsigned r = v.u + 0x7FFFu + ((v.u >> 16) & 1u);
  return (unsigned short)(r >> 16);
}
DEV float bf2f(unsigned short h) {
  union { unsigned u; float f; } v; v.u = ((unsigned)h) << 16;
  return v.f;
}

#define MFMA16x32(a, b, c) __builtin_amdgcn_mfma_f32_16x16x32_bf16((a), (b), (c), 0, 0, 0)

DEV void gload_lds16(const unsigned short* g, unsigned short* l) {
  __builtin_amdgcn_global_load_lds(
      (const __attribute__((address_space(1))) void*)g,
      (__attribute__((address_space(3))) void*)l, 16, 0, 0);
}

// ---------------- fp32 -> bf16 convert ----------------
__global__ __launch_bounds__(256) void k_cvt(const float* __restrict__ in,
                                             unsigned short* __restrict__ out, int n4) {
  int i = blockIdx.x * 256 + threadIdx.x;
  if (i >= n4) return;
  float4v v = ((const float4v*)in)[i];
  ushort4v o;
  o[0] = f2bf(v[0]); o[1] = f2bf(v[1]); o[2] = f2bf(v[2]); o[3] = f2bf(v[3]);
  ((ushort4v*)out)[i] = o;
}

// ---------------- RoPE cos/sin table: [B*S][32] ----------------
__global__ __launch_bounds__(256) void k_tab(const int* __restrict__ pos,
                                             float* __restrict__ tc, float* __restrict__ ts) {
  int i = blockIdx.x * 256 + threadIdx.x;   // B*S*32 total
  int t = i >> 5, fi = i & 31;
  float p = (float)pos[t];
  float inv = powf(10000.0f, -(float)fi / 32.0f);
  float a = p * inv;
  float sv, cv;
  sincosf(a, &sv, &cv);
  tc[i] = cv;
  ts[i] = sv;
}

// ---------------- RoPE in-place on Q and K ([bh][s][64] bf16) ----------------
__global__ __launch_bounds__(256) void k_rope(unsigned short* __restrict__ Q,
                                              unsigned short* __restrict__ K,
                                              const float* __restrict__ tc,
                                              const float* __restrict__ ts) {
  int idx = blockIdx.x * 256 + threadIdx.x;   // bh*2048 + s, total 131072
  int bh = idx >> 11, s = idx & 2047, b = bh >> 4;
  const float* tcp = tc + ((size_t)(b * SS + s)) * 32;
  const float* tsp = ts + ((size_t)(b * SS + s)) * 32;
  size_t base = (size_t)idx * 64;
  for (int which = 0; which < 2; ++which) {
    unsigned short* P = which ? K : Q;
    short8* rp = (short8*)(P + base);
#pragma unroll
    for (int ch = 0; ch < 8; ++ch) {
      short8 v = rp[ch];
      short8 r;
#pragma unroll
      for (int p = 0; p < 4; ++p) {
        int pi = ch * 4 + p;
        float e = bf2f((unsigned short)v[2 * p]);
        float o = bf2f((unsigned short)v[2 * p + 1]);
        float c = tcp[pi], sn = tsp[pi];
        r[2 * p]     = (short)f2bf(e * c - o * sn);
        r[2 * p + 1] = (short)f2bf(e * sn + o * c);
      }
      rp[ch] = r;
    }
  }
}

// ---------------- bf16 GEMM, B^T layout: C[m][n] = sum_k A[m][k]*B[n][k] + bias[n]
// MODE 0: out0 = fp32 [M][N]
// MODE 1: qkv scatter: out0=Q [b,h,s,d], out1=K [b,h,s,d], out2=Vt [b,h,d,s], all bf16
template <int MODE>
__global__ __launch_bounds__(256) void k_gemm_bt(
    const unsigned short* __restrict__ A, const unsigned short* __restrict__ Bm,
    const float* __restrict__ bias, void* __restrict__ out0, void* __restrict__ out1,
    void* __restrict__ out2, int M, int N, int K) {
  __shared__ __align__(16) unsigned short As[128 * 64];
  __shared__ __align__(16) unsigned short Bs[128 * 64];
  int wid = threadIdx.x >> 6, lane = threadIdx.x & 63;
  int l16 = lane & 15, lq = lane >> 4;
  int m0 = blockIdx.y * 128, n0 = blockIdx.x * 128;
  int wr = wid >> 1, wc = wid & 1;

  f32x4 acc[4][4];
#pragma unroll
  for (int i = 0; i < 4; i++)
#pragma unroll
    for (int j = 0; j < 4; j++) acc[i][j] = (f32x4){0.f, 0.f, 0.f, 0.f};

  int c0 = wid * 4;
  int srow = lane >> 3;          // 0..7
  int skcol = (lane & 7) * 8;    // 0..56
  int nkt = K >> 6;
  for (int kt = 0; kt < nkt; ++kt) {
    int k0 = kt << 6;
    __syncthreads();
#pragma unroll
    for (int i = 0; i < 4; ++i) {
      int c = c0 + i;
      const unsigned short* sa = A + (size_t)(m0 + c * 8 + srow) * K + (k0 + skcol);
      gload_lds16(sa, &As[c * 512]);
      const unsigned short* sb = Bm + (size_t)(n0 + c * 8 + srow) * K + (k0 + skcol);
      gload_lds16(sb, &Bs[c * 512]);
    }
    __syncthreads();
#pragma unroll
    for (int kk = 0; kk < 2; ++kk) {
      int ko = kk * 32 + lq * 8;
      short8 af[4], bfr[4];
#pragma unroll
      for (int mi = 0; mi < 4; ++mi)
        af[mi] = *(const short8*)&As[(wr * 64 + mi * 16 + l16) * 64 + ko];
#pragma unroll
      for (int ni = 0; ni < 4; ++ni)
        bfr[ni] = *(const short8*)&Bs[(wc * 64 + ni * 16 + l16) * 64 + ko];
#pragma unroll
      for (int mi = 0; mi < 4; ++mi)
#pragma unroll
        for (int ni = 0; ni < 4; ++ni)
          acc[mi][ni] = MFMA16x32(af[mi], bfr[ni], acc[mi][ni]);
    }
  }

  if (MODE == 0) {
    float* C = (float*)out0;
#pragma unroll
    for (int mi = 0; mi < 4; ++mi) {
      int row = m0 + wr * 64 + mi * 16 + lq * 4;
#pragma unroll
      for (int ni = 0; ni < 4; ++ni) {
        int col = n0 + wc * 64 + ni * 16 + l16;
        float bv = bias[col];
#pragma unroll
        for (int j = 0; j < 4; ++j)
          C[(size_t)(row + j) * N + col] = acc[mi][ni][j] + bv;
      }
    }
  } else {
    unsigned short* Qb = (unsigned short*)out0;
    unsigned short* Kb = (unsigned short*)out1;
    unsigned short* Vt = (unsigned short*)out2;
#pragma unroll
    for (int mi = 0; mi < 4; ++mi) {
      int row = m0 + wr * 64 + mi * 16 + lq * 4;   // token index base
      int b = row >> 11, s = row & 2047;
#pragma unroll
      for (int ni = 0; ni < 4; ++ni) {
        int col = n0 + wc * 64 + ni * 16 + l16;
        int sel = col >> 10;
        int hh = (col >> 6) & 15;
        int d = col & 63;
        float bv = bias[col];
        if (sel < 2) {
          unsigned short* P = sel ? Kb : Qb;
          size_t p = ((size_t)(b * NH + hh) * SS + s) * 64 + d;
#pragma unroll
          for (int j = 0; j < 4; ++j)
            P[p + (size_t)j * 64] = f2bf(acc[mi][ni][j] + bv);
        } else {
          size_t p = ((size_t)(b * NH + hh) * 64 + d) * SS + s;
          ushort4v o;
#pragma unroll
          for (int j = 0; j < 4; ++j) o[j] = f2bf(acc[mi][ni][j] + bv);
          *(ushort4v*)&Vt[p] = o;
        }
      }
    }
  }
}

// ---------------- causal flash attention ----------------
// Q,K: [bh][s][64] bf16 (roped); Vt: [bh][64][s] bf16; H out: [b][s][1024] bf16
__global__ __launch_bounds__(256) void k_attn(const unsigned short* __restrict__ Q,
                                              const unsigned short* __restrict__ K,
                                              const unsigned short* __restrict__ Vt,
                                              unsigned short* __restrict__ H) {
  __shared__ __align__(16) unsigned short plds[4][16][64];
  int qt = blockIdx.x;    // 0..31
  int bh = blockIdx.y;    // 0..63
  int b = bh >> 4, h = bh & 15;
  int wid = threadIdx.x >> 6, lane = threadIdx.x & 63;
  int l16 = lane & 15, lq = lane >> 4;
  const unsigned short* Qh = Q + (size_t)bh * SS * 64;
  const unsigned short* Kh = K + (size_t)bh * SS * 64;
  const unsigned short* Vh = Vt + (size_t)bh * 64 * SS;
  int q0 = qt * 64 + wid * 16;

  short8 aq[2];
  {
    int qrow = q0 + l16;
    aq[0] = *(const short8*)(Qh + (size_t)qrow * 64 + lq * 8);
    aq[1] = *(const short8*)(Qh + (size_t)qrow * 64 + 32 + lq * 8);
  }
  f32x4 o[4];
  float m[4], lsum[4];
#pragma unroll
  for (int i = 0; i < 4; i++) {
    o[i] = (f32x4){0.f, 0.f, 0.f, 0.f};
    m[i] = -1e30f;
    lsum[i] = 0.f;
  }
  int ntiles = qt + 1;
  for (int kt = 0; kt < ntiles; ++kt) {
    int kb = kt << 6;
    f32x4 sacc[4];
#pragma unroll
    for (int nb = 0; nb < 4; ++nb) {
      sacc[nb] = (f32x4){0.f, 0.f, 0.f, 0.f};
      const unsigned short* kp = Kh + (size_t)(kb + nb * 16 + l16) * 64 + lq * 8;
      short8 bk0 = *(const short8*)kp;
      short8 bk1 = *(const short8*)(kp + 32);
      sacc[nb] = MFMA16x32(aq[0], bk0, sacc[nb]);
      sacc[nb] = MFMA16x32(aq[1], bk1, sacc[nb]);
    }
    bool diag = (kt == qt - 0) && (kt * 64 + 63 > q0);  // only last tile can mask
    float tmax[4];
#pragma unroll
    for (int j = 0; j < 4; ++j) tmax[j] = -1e30f;
#pragma unroll
    for (int nb = 0; nb < 4; ++nb) {
#pragma unroll
      for (int j = 0; j < 4; ++j) {
        float s = sacc[nb][j] * 0.125f;
        if (diag) {
          int key = kb + nb * 16 + l16;
          int qrow = q0 + lq * 4 + j;
          if (key > qrow) s = -1e30f;
        }
        sacc[nb][j] = s;
        tmax[j] = fmaxf(tmax[j], s);
      }
    }
#pragma unroll
    for (int j = 0; j < 4; ++j) {
#pragma unroll
      for (int msk = 1; msk < 16; msk <<= 1)
        tmax[j] = fmaxf(tmax[j], __shfl_xor(tmax[j], msk, 64));
    }
    float fac[4], rsum[4];
#pragma unroll
    for (int j = 0; j < 4; ++j) {
      float mn = fmaxf(m[j], tmax[j]);
      fac[j] = __expf(m[j] - mn);
      m[j] = mn;
      rsum[j] = 0.f;
    }
#pragma unroll
    for (int nb = 0; nb < 4; ++nb) {
#pragma unroll
      for (int j = 0; j < 4; ++j) {
        float p = __expf(sacc[nb][j] - m[j]);
        sacc[nb][j] = p;
        rsum[j] += p;
      }
    }
#pragma unroll
    for (int j = 0; j < 4; ++j) {
#pragma unroll
      for (int msk = 1; msk < 16; msk <<= 1)
        rsum[j] += __shfl_xor(rsum[j], msk, 64);
      lsum[j] = lsum[j] * fac[j] + rsum[j];
    }
#pragma unroll
    for (int ni = 0; ni < 4; ++ni)
#pragma unroll
      for (int j = 0; j < 4; ++j) o[ni][j] *= fac[j];
    // stage P through LDS to re-layout as MFMA A operand
#pragma unroll
    for (int nb = 0; nb < 4; ++nb)
#pragma unroll
      for (int j = 0; j < 4; ++j)
        plds[wid][lq * 4 + j][nb * 16 + l16] = f2bf(sacc[nb][j]);
    __syncthreads();
    short8 ap[2];
    ap[0] = *(const short8*)&plds[wid][l16][lq * 8];
    ap[1] = *(const short8*)&plds[wid][l16][32 + lq * 8];
#pragma unroll
    for (int ni = 0; ni < 4; ++ni) {
      const unsigned short* vp = Vh + (size_t)(ni * 16 + l16) * SS + kb + lq * 8;
      short8 bv0 = *(const short8*)vp;
      short8 bv1 = *(const short8*)(vp + 32);
      o[ni] = MFMA16x32(ap[0], bv0, o[ni]);
      o[ni] = MFMA16x32(ap[1], bv1, o[ni]);
    }
    __syncthreads();
  }
#pragma unroll
  for (int ni = 0; ni < 4; ++ni) {
    int d = h * 64 + ni * 16 + l16;
#pragma unroll
    for (int j = 0; j < 4; ++j) {
      int s = q0 + lq * 4 + j;
      float v = o[ni][j] / lsum[j];
      H[((size_t)(b * SS + s)) * 1024 + d] = f2bf(v);
    }
  }
}

extern "C" void kernel_launch(void* const* d_in, const int* in_sizes, int n_in,
                              void* d_out, int out_size, void* d_ws, size_t ws_size,
                              hipStream_t stream) {
  const float* x    = (const float*)d_in[0];
  const int*   pos  = (const int*)d_in[1];
  const float* Wqkv = (const float*)d_in[2];
  const float* bqkv = (const float*)d_in[3];
  const float* Wo   = (const float*)d_in[4];
  const float* bo   = (const float*)d_in[5];
  float* out = (float*)d_out;

  char* w = (char*)d_ws;
  unsigned short* x_bf    = (unsigned short*)(w + 0);          // 16 MB [8192][1024]
  unsigned short* h_bf    = x_bf;                              // alias (x dead after gemm1)
  unsigned short* wqkv_bf = (unsigned short*)(w + 16777216);   // 6 MB [3072][1024]
  unsigned short* wo_bf   = (unsigned short*)(w + 23068672);   // 2 MB [1024][1024]
  unsigned short* Qb      = (unsigned short*)(w + 25165824);   // 16 MB [64][2048][64]
  unsigned short* Kb      = (unsigned short*)(w + 41943040);   // 16 MB
  unsigned short* Vt      = (unsigned short*)(w + 58720256);   // 16 MB [64][64][2048]
  float* tabc             = (float*)(w + 75497472);            // 1 MB [8192][32]
  float* tabs             = (float*)(w + 76546048);            // 1 MB

  k_cvt<<<8192, 256, 0, stream>>>(x, x_bf, 2097152);
  k_cvt<<<3072, 256, 0, stream>>>(Wqkv, wqkv_bf, 786432);
  k_cvt<<<1024, 256, 0, stream>>>(Wo, wo_bf, 262144);
  k_tab<<<1024, 256, 0, stream>>>(pos, tabc, tabs);
  k_gemm_bt<1><<<dim3(24, 64), 256, 0, stream>>>(x_bf, wqkv_bf, bqkv, Qb, Kb, Vt, TOK, 3072, DM);
  k_rope<<<512, 256, 0, stream>>>(Qb, Kb, tabc, tabs);
  k_attn<<<dim3(32, 64), 256, 0, stream>>>(Qb, Kb, Vt, h_bf);
  k_gemm_bt<0><<<dim3(8, 64), 256, 0, stream>>>(h_bf, wo_bf, bo, out, nullptr, nullptr, TOK, DM, DM);
}

// Round 2
// 434.659 us; speedup vs baseline: 1.4360x; 1.4360x over previous
//
#include <hip/hip_runtime.h>

#define DEV static __device__ __forceinline__

typedef __attribute__((ext_vector_type(8))) short short8;
typedef __attribute__((ext_vector_type(4))) float f32x4;
typedef __attribute__((ext_vector_type(4))) unsigned short ushort4v;
typedef __attribute__((ext_vector_type(4))) float float4v;

#define DM 1024
#define NH 16
#define HD 64
#define NB 4
#define SS 2048
#define TOK 8192

DEV unsigned short f2bf(float f) {
  union { float f; unsigned u; } v; v.f = f;
  unsigned r = v.u + 0x7FFFu + ((v.u >> 16) & 1u);
  return (unsigned short)(r >> 16);
}
DEV float bf2f(unsigned short h) {
  union { unsigned u; float f; } v; v.u = ((unsigned)h) << 16;
  return v.f;
}

#define MFMA16x32(a, b, c) __builtin_amdgcn_mfma_f32_16x16x32_bf16((a), (b), (c), 0, 0, 0)

DEV void gload_lds16(const unsigned short* g, unsigned short* l) {
  __builtin_amdgcn_global_load_lds(
      (const __attribute__((address_space(1))) void*)g,
      (__attribute__((address_space(3))) void*)l, 16, 0, 0);
}

// ---------------- fp32 -> bf16 convert ----------------
__global__ __launch_bounds__(256) void k_cvt(const float* __restrict__ in,
                                             unsigned short* __restrict__ out, int n4) {
  int i = blockIdx.x * 256 + threadIdx.x;
  if (i >= n4) return;
  float4v v = ((const float4v*)in)[i];
  ushort4v o;
  o[0] = f2bf(v[0]); o[1] = f2bf(v[1]); o[2] = f2bf(v[2]); o[3] = f2bf(v[3]);
  ((ushort4v*)out)[i] = o;
}

// ---------------- RoPE cos/sin table: [B*S][32] ----------------
__global__ __launch_bounds__(256) void k_tab(const int* __restrict__ pos,
                                             float* __restrict__ tc, float* __restrict__ ts) {
  int i = blockIdx.x * 256 + threadIdx.x;   // B*S*32 total
  int t = i >> 5, fi = i & 31;
  float p = (float)pos[t];
  float inv = powf(10000.0f, -(float)fi / 32.0f);
  float a = p * inv;
  float sv, cv;
  sincosf(a, &sv, &cv);
  tc[i] = cv;
  ts[i] = sv;
}

// ---------------- RoPE in-place on Q and K ([bh][s][64] bf16) ----------------
__global__ __launch_bounds__(256) void k_rope(unsigned short* __restrict__ Q,
                                              unsigned short* __restrict__ K,
                                              const float* __restrict__ tc,
                                              const float* __restrict__ ts) {
  int idx = blockIdx.x * 256 + threadIdx.x;   // bh*2048 + s, total 131072
  int bh = idx >> 11, s = idx & 2047, b = bh >> 4;
  const float* tcp = tc + ((size_t)(b * SS + s)) * 32;
  const float* tsp = ts + ((size_t)(b * SS + s)) * 32;
  size_t base = (size_t)idx * 64;
  for (int which = 0; which < 2; ++which) {
    unsigned short* P = which ? K : Q;
    short8* rp = (short8*)(P + base);
#pragma unroll
    for (int ch = 0; ch < 8; ++ch) {
      short8 v = rp[ch];
      short8 r;
#pragma unroll
      for (int p = 0; p < 4; ++p) {
        int pi = ch * 4 + p;
        float e = bf2f((unsigned short)v[2 * p]);
        float o = bf2f((unsigned short)v[2 * p + 1]);
        float c = tcp[pi], sn = tsp[pi];
        r[2 * p]     = (short)f2bf(e * c - o * sn);
        r[2 * p + 1] = (short)f2bf(e * sn + o * c);
      }
      rp[ch] = r;
    }
  }
}

// ---------------- bf16 GEMM, B^T layout: C[m][n] = sum_k A[m][k]*B[n][k] + bias[n]
// MODE 0: out0 = fp32 [M][N]
// MODE 1: qkv scatter: out0=Q [b,h,s,d], out1=K [b,h,s,d], out2=Vt [b,h,d,s], all bf16
template <int MODE>
__global__ __launch_bounds__(256) void k_gemm_bt(
    const unsigned short* __restrict__ A, const unsigned short* __restrict__ Bm,
    const float* __restrict__ bias, void* __restrict__ out0, void* __restrict__ out1,
    void* __restrict__ out2, int M, int N, int K) {
  __shared__ __align__(16) unsigned short As[128 * 64];
  __shared__ __align__(16) unsigned short Bs[128 * 64];
  int wid = threadIdx.x >> 6, lane = threadIdx.x & 63;
  int l16 = lane & 15, lq = lane >> 4;
  int m0 = blockIdx.y * 128, n0 = blockIdx.x * 128;
  int wr = wid >> 1, wc = wid & 1;

  f32x4 acc[4][4];
#pragma unroll
  for (int i = 0; i < 4; i++)
#pragma unroll
    for (int j = 0; j < 4; j++) acc[i][j] = (f32x4){0.f, 0.f, 0.f, 0.f};

  int c0 = wid * 4;
  int srow = lane >> 3;          // 0..7
  int skcol = (lane & 7) * 8;    // 0..56
  int nkt = K >> 6;
  for (int kt = 0; kt < nkt; ++kt) {
    int k0 = kt << 6;
    __syncthreads();
#pragma unroll
    for (int i = 0; i < 4; ++i) {
      int c = c0 + i;
      const unsigned short* sa = A + (size_t)(m0 + c * 8 + srow) * K + (k0 + skcol);
      gload_lds16(sa, &As[c * 512]);
      const unsigned short* sb = Bm + (size_t)(n0 + c * 8 + srow) * K + (k0 + skcol);
      gload_lds16(sb, &Bs[c * 512]);
    }
    __syncthreads();
#pragma unroll
    for (int kk = 0; kk < 2; ++kk) {
      int ko = kk * 32 + lq * 8;
      short8 af[4], bfr[4];
#pragma unroll
      for (int mi = 0; mi < 4; ++mi)
        af[mi] = *(const short8*)&As[(wr * 64 + mi * 16 + l16) * 64 + ko];
#pragma unroll
      for (int ni = 0; ni < 4; ++ni)
        bfr[ni] = *(const short8*)&Bs[(wc * 64 + ni * 16 + l16) * 64 + ko];
#pragma unroll
      for (int mi = 0; mi < 4; ++mi)
#pragma unroll
        for (int ni = 0; ni < 4; ++ni)
          acc[mi][ni] = MFMA16x32(af[mi], bfr[ni], acc[mi][ni]);
    }
  }

  if (MODE == 0) {
    float* C = (float*)out0;
#pragma unroll
    for (int mi = 0; mi < 4; ++mi) {
      int row = m0 + wr * 64 + mi * 16 + lq * 4;
#pragma unroll
      for (int ni = 0; ni < 4; ++ni) {
        int col = n0 + wc * 64 + ni * 16 + l16;
        float bv = bias[col];
#pragma unroll
        for (int j = 0; j < 4; ++j)
          C[(size_t)(row + j) * N + col] = acc[mi][ni][j] + bv;
      }
    }
  } else {
    unsigned short* Qb = (unsigned short*)out0;
    unsigned short* Kb = (unsigned short*)out1;
    unsigned short* Vt = (unsigned short*)out2;
#pragma unroll
    for (int mi = 0; mi < 4; ++mi) {
      int row = m0 + wr * 64 + mi * 16 + lq * 4;   // token index base
      int b = row >> 11, s = row & 2047;
#pragma unroll
      for (int ni = 0; ni < 4; ++ni) {
        int col = n0 + wc * 64 + ni * 16 + l16;
        int sel = col >> 10;
        int hh = (col >> 6) & 15;
        int d = col & 63;
        float bv = bias[col];
        if (sel < 2) {
          unsigned short* P = sel ? Kb : Qb;
          size_t p = ((size_t)(b * NH + hh) * SS + s) * 64 + d;
#pragma unroll
          for (int j = 0; j < 4; ++j)
            P[p + (size_t)j * 64] = f2bf(acc[mi][ni][j] + bv);
        } else {
          size_t p = ((size_t)(b * NH + hh) * 64 + d) * SS + s;
          ushort4v o;
#pragma unroll
          for (int j = 0; j < 4; ++j) o[j] = f2bf(acc[mi][ni][j] + bv);
          *(ushort4v*)&Vt[p] = o;
        }
      }
    }
  }
}

// ---------------- causal flash attention ----------------
// Q,K: [bh][s][64] bf16 (roped); Vt: [bh][64][s] bf16; H out: [b][s][1024] bf16
// Each wave is fully independent (plds slice is wave-private -> NO barriers).
// Blocks pair q-tiles (z, 31-z) so every block does exactly 33 KV tiles.
__global__ __launch_bounds__(256) void k_attn(const unsigned short* __restrict__ Q,
                                              const unsigned short* __restrict__ K,
                                              const unsigned short* __restrict__ Vt,
                                              unsigned short* __restrict__ H) {
  __shared__ __align__(16) unsigned short plds[4][16][64];
  int z = blockIdx.x;     // 0..15
  int bh = blockIdx.y;    // 0..63
  int b = bh >> 4, h = bh & 15;
  int wid = threadIdx.x >> 6, lane = threadIdx.x & 63;
  int l16 = lane & 15, lq = lane >> 4;
  const unsigned short* Qh = Q + (size_t)bh * SS * 64;
  const unsigned short* Kh = K + (size_t)bh * SS * 64;
  const unsigned short* Vh = Vt + (size_t)bh * 64 * SS;
  unsigned short (*pw)[64] = plds[wid];

  for (int seg = 0; seg < 2; ++seg) {
    int qt = seg ? (31 - z) : z;
    int q0 = qt * 64 + wid * 16;

    short8 aq[2];
    {
      int qrow = q0 + l16;
      aq[0] = *(const short8*)(Qh + (size_t)qrow * 64 + lq * 8);
      aq[1] = *(const short8*)(Qh + (size_t)qrow * 64 + 32 + lq * 8);
    }
    f32x4 o[4];
    float m[4], lsum[4];
#pragma unroll
    for (int i = 0; i < 4; i++) {
      o[i] = (f32x4){0.f, 0.f, 0.f, 0.f};
      m[i] = -1e30f;
      lsum[i] = 0.f;
    }
    for (int kt = 0; kt <= qt; ++kt) {
      int kb = kt << 6;
      // QK^T
      f32x4 sacc[4];
#pragma unroll
      for (int nb = 0; nb < 4; ++nb) {
        sacc[nb] = (f32x4){0.f, 0.f, 0.f, 0.f};
        const unsigned short* kp = Kh + (size_t)(kb + nb * 16 + l16) * 64 + lq * 8;
        short8 bk0 = *(const short8*)kp;
        short8 bk1 = *(const short8*)(kp + 32);
        sacc[nb] = MFMA16x32(aq[0], bk0, sacc[nb]);
        sacc[nb] = MFMA16x32(aq[1], bk1, sacc[nb]);
      }
      // V prefetch (independent of scores) — hides L2 latency under softmax
      short8 bv[4][2];
#pragma unroll
      for (int ni = 0; ni < 4; ++ni) {
        const unsigned short* vp = Vh + (size_t)(ni * 16 + l16) * SS + kb + lq * 8;
        bv[ni][0] = *(const short8*)vp;
        bv[ni][1] = *(const short8*)(vp + 32);
      }
      bool diag = (kt == qt);
      float tmax[4];
#pragma unroll
      for (int j = 0; j < 4; ++j) tmax[j] = -1e30f;
#pragma unroll
      for (int nb = 0; nb < 4; ++nb) {
#pragma unroll
        for (int j = 0; j < 4; ++j) {
          float s = sacc[nb][j] * 0.125f;
          if (diag) {
            int key = kb + nb * 16 + l16;
            int qrow = q0 + lq * 4 + j;
            if (key > qrow) s = -1e30f;
          }
          sacc[nb][j] = s;
          tmax[j] = fmaxf(tmax[j], s);
        }
      }
#pragma unroll
      for (int j = 0; j < 4; ++j) {
#pragma unroll
        for (int msk = 1; msk < 16; msk <<= 1)
          tmax[j] = fmaxf(tmax[j], __shfl_xor(tmax[j], msk, 64));
      }
      float fac[4], rsum[4];
#pragma unroll
      for (int j = 0; j < 4; ++j) {
        float mn = fmaxf(m[j], tmax[j]);
        fac[j] = __expf(m[j] - mn);
        m[j] = mn;
        rsum[j] = 0.f;
      }
#pragma unroll
      for (int nb = 0; nb < 4; ++nb) {
#pragma unroll
        for (int j = 0; j < 4; ++j) {
          float p = __expf(sacc[nb][j] - m[j]);
          sacc[nb][j] = p;
          rsum[j] += p;
        }
      }
#pragma unroll
      for (int j = 0; j < 4; ++j) {
#pragma unroll
        for (int msk = 1; msk < 16; msk <<= 1)
          rsum[j] += __shfl_xor(rsum[j], msk, 64);
        lsum[j] = lsum[j] * fac[j] + rsum[j];
      }
#pragma unroll
      for (int ni = 0; ni < 4; ++ni)
#pragma unroll
        for (int j = 0; j < 4; ++j) o[ni][j] *= fac[j];
      // stage P through wave-private LDS (chunk-XOR swizzled, no barriers needed)
#pragma unroll
      for (int nb = 0; nb < 4; ++nb)
#pragma unroll
        for (int j = 0; j < 4; ++j) {
          int row = lq * 4 + j;
          int col = nb * 16 + l16;
          int sw = ((col >> 3) ^ (row & 7)) * 8 + (col & 7);
          pw[row][sw] = f2bf(sacc[nb][j]);
        }
      short8 ap[2];
      ap[0] = *(const short8*)&pw[l16][(lq ^ (l16 & 7)) * 8];
      ap[1] = *(const short8*)&pw[l16][((lq + 4) ^ (l16 & 7)) * 8];
#pragma unroll
      for (int ni = 0; ni < 4; ++ni) {
        o[ni] = MFMA16x32(ap[0], bv[ni][0], o[ni]);
        o[ni] = MFMA16x32(ap[1], bv[ni][1], o[ni]);
      }
    }
#pragma unroll
    for (int ni = 0; ni < 4; ++ni) {
      int d = h * 64 + ni * 16 + l16;
#pragma unroll
      for (int j = 0; j < 4; ++j) {
        int s = q0 + lq * 4 + j;
        float v = o[ni][j] / lsum[j];
        H[((size_t)(b * SS + s)) * 1024 + d] = f2bf(v);
      }
    }
  }
}

extern "C" void kernel_launch(void* const* d_in, const int* in_sizes, int n_in,
                              void* d_out, int out_size, void* d_ws, size_t ws_size,
                              hipStream_t stream) {
  const float* x    = (const float*)d_in[0];
  const int*   pos  = (const int*)d_in[1];
  const float* Wqkv = (const float*)d_in[2];
  const float* bqkv = (const float*)d_in[3];
  const float* Wo   = (const float*)d_in[4];
  const float* bo   = (const float*)d_in[5];
  float* out = (float*)d_out;

  char* w = (char*)d_ws;
  unsigned short* x_bf    = (unsigned short*)(w + 0);          // 16 MB [8192][1024]
  unsigned short* h_bf    = x_bf;                              // alias (x dead after gemm1)
  unsigned short* wqkv_bf = (unsigned short*)(w + 16777216);   // 6 MB [3072][1024]
  unsigned short* wo_bf   = (unsigned short*)(w + 23068672);   // 2 MB [1024][1024]
  unsigned short* Qb      = (unsigned short*)(w + 25165824);   // 16 MB [64][2048][64]
  unsigned short* Kb      = (unsigned short*)(w + 41943040);   // 16 MB
  unsigned short* Vt      = (unsigned short*)(w + 58720256);   // 16 MB [64][64][2048]
  float* tabc             = (float*)(w + 75497472);            // 1 MB [8192][32]
  float* tabs             = (float*)(w + 76546048);            // 1 MB

  k_cvt<<<8192, 256, 0, stream>>>(x, x_bf, 2097152);
  k_cvt<<<3072, 256, 0, stream>>>(Wqkv, wqkv_bf, 786432);
  k_cvt<<<1024, 256, 0, stream>>>(Wo, wo_bf, 262144);
  k_tab<<<1024, 256, 0, stream>>>(pos, tabc, tabs);
  k_gemm_bt<1><<<dim3(24, 64), 256, 0, stream>>>(x_bf, wqkv_bf, bqkv, Qb, Kb, Vt, TOK, 3072, DM);
  k_rope<<<512, 256, 0, stream>>>(Qb, Kb, tabc, tabs);
  k_attn<<<dim3(16, 64), 256, 0, stream>>>(Qb, Kb, Vt, h_bf);
  k_gemm_bt<0><<<dim3(8, 64), 256, 0, stream>>>(h_bf, wo_bf, bo, out, nullptr, nullptr, TOK, DM, DM);
}